// Round 2
// baseline (241.693 us; speedup 1.0000x reference)
//
#include <hip/hip_runtime.h>
#include <hip/hip_bf16.h>
#include <stdint.h>

#define NB 8
#define NP 12000
#define NM 32
#define NF 9
#define NC 64
#define NX 144
#define NCELL (144*144)          // 20736 = 64*324

#define PPW 8                    // pillars per wave
#define FEAT_WAVES ((NB*NP)/PPW) // 12000 worst-case waves
#define FEAT_BLOCKS (FEAT_WAVES/4)
#define TILES_PER_B (NCELL/64)   // 324

typedef __attribute__((ext_vector_type(8)))  short bfrag8;
typedef __attribute__((ext_vector_type(16))) float accf16;
typedef float f32x4u __attribute__((ext_vector_type(4), aligned(4)));

// ws layout:
//   [0,2048)        btab: 2 c-tiles x 64 lanes x 8 bf16 (B-frag, BN-folded)
//   [2048,2304)     shift[c]
//   [2304,2308)     cnt: winner-list atomic counter
//   [4096,667648)   winner[b][cell] (8*20736 ints)
//   [667648,1435648) list: up to 96000 int2 (cell_b, pillar_global)
//   [1435648,+42.47M) feat_cell[(b*NCELL+cell)*64 + c]  (winner cells only)
#define WS_BTAB  0
#define WS_SHIFT 2048
#define WS_CNT   2304
#define WS_WIN   4096
#define WS_LIST  667648
#define WS_CELL  1435648
#define WS_NEED  (WS_CELL + (size_t)NB*NCELL*NC*4)

// Pass 1: last-write-wins winner (largest p wins) + BN-folded weight prep.
__global__ void winner_prep_kernel(const int* __restrict__ idx, int* __restrict__ winner,
                                   const float* __restrict__ conv_w,
                                   const float* __restrict__ gamma,
                                   const float* __restrict__ beta,
                                   const float* __restrict__ mean,
                                   const float* __restrict__ var,
                                   unsigned short* __restrict__ btab,
                                   float* __restrict__ shift,
                                   int* __restrict__ cnt)
{
    int t = blockIdx.x * blockDim.x + threadIdx.x;
    if (t < NB * NP) {
        int b = t / NP;
        int p = t - b * NP;
        int y = idx[t * 3 + 1];
        int x = idx[t * 3 + 2];
        x = x < 0 ? 0 : (x > 143 ? 143 : x);
        y = y < 0 ? 0 : (y > 143 ? 143 : y);
        atomicMax(&winner[b * NCELL + y * NX + x], p);   // init = -1
    }
    if (blockIdx.x == 0) {
        int tt = threadIdx.x;
        if (tt < 128) {
            int ct = tt >> 6, L = tt & 63;
            int c  = ct * 32 + (L & 31);
            int kq = L >> 5;
            float sc = gamma[c] * rsqrtf(var[c] + 1e-5f);
            unsigned short* dst = btab + (ct * 64 + L) * 8;
            #pragma unroll
            for (int j = 0; j < 8; ++j) {
                int k = kq * 8 + j;
                float w = (k < NF) ? conv_w[c * NF + k] * sc : 0.f;
                __hip_bfloat16 h = __float2bfloat16(w);
                dst[j] = *(unsigned short*)&h;
            }
        }
        if (tt < NC) {
            float sc = gamma[tt] * rsqrtf(var[tt] + 1e-5f);
            shift[tt] = beta[tt] - mean[tt] * sc;
        }
        if (tt == 200) *cnt = 0;   // consumed only by later dispatches
    }
}

// Pass 1b: compact (cell, pillar) winner pairs into a dense list.
// ~72.9K of 165888 cells survive; atomicAdd(p,1) is wave-aggregated by the
// compiler (mbcnt trick), so this is ~2.6K wave-level atomics.
__global__ void compact_kernel(const int* __restrict__ winner,
                               int* __restrict__ cnt,
                               int2* __restrict__ list)
{
    int cell_b = blockIdx.x * blockDim.x + threadIdx.x;
    if (cell_b < NB * NCELL) {
        int w = winner[cell_b];
        if (w >= 0) {
            int b = cell_b / NCELL;
            int pos = atomicAdd(cnt, 1);
            list[pos] = make_int2(cell_b, b * NP + w);
        }
    }
}

__device__ __forceinline__ float max16(const accf16& a) {
    float t0 = fmaxf(fmaxf(a[0], a[1]),  fmaxf(a[2], a[3]));
    float t1 = fmaxf(fmaxf(a[4], a[5]),  fmaxf(a[6], a[7]));
    float t2 = fmaxf(fmaxf(a[8], a[9]),  fmaxf(a[10], a[11]));
    float t3 = fmaxf(fmaxf(a[12], a[13]), fmaxf(a[14], a[15]));
    return fmaxf(fmaxf(t0, t1), fmaxf(t2, t3));
}

// Pass 2 (compact): winner-only conv+max. Each wave takes 8 list entries;
// last wave clamps to entry n-1 (duplicate stores are idempotent — same
// address, same value — so no per-entry guards in the hot loop).
__global__ void __launch_bounds__(256) feat_list_kernel(
    const float* __restrict__ pillars,
    const unsigned short* __restrict__ btab,
    const float* __restrict__ shift,
    const int*  __restrict__ cnt,
    const int2* __restrict__ list,
    float* __restrict__ feat_cell)
{
    int tid  = threadIdx.x;
    int lane = tid & 63;
    int wave = blockIdx.x * 4 + (tid >> 6);
    int n    = *cnt;
    int base = wave * PPW;
    if (base >= n) return;                     // ~24% of waves exit here

    int row = lane & 31;
    int kq  = lane >> 5;

    bfrag8 b0 = *(const bfrag8*)(btab + lane * 8);
    bfrag8 b1 = *(const bfrag8*)(btab + (64 + lane) * 8);
    float  sh = shift[lane];
    accf16 z  = {};

    int2 ent[PPW];
    #pragma unroll
    for (int i = 0; i < PPW; ++i) {
        int j = base + i;
        j = j < n - 1 ? j : n - 1;             // clamp -> idempotent dup
        ent[i] = list[j];
    }

    #pragma unroll
    for (int g = 0; g < PPW / 4; ++g) {
        f32x4u lo[4], hi[4];
        float  e8[4];
        #pragma unroll
        for (int i = 0; i < 4; ++i) {
            const float* bp = pillars + (size_t)ent[g * 4 + i].y * (NM * NF) + row * NF;
            lo[i] = *(const f32x4u*)(bp);
            hi[i] = *(const f32x4u*)(bp + 4);
            e8[i] = bp[8];
        }
        #pragma unroll
        for (int i = 0; i < 4; ++i) {
            int pi = g * 4 + i;
            float s[8];
            s[0] = kq ? e8[i] : lo[i][0];
            s[1] = kq ? 0.f   : lo[i][1];
            s[2] = kq ? 0.f   : lo[i][2];
            s[3] = kq ? 0.f   : lo[i][3];
            s[4] = kq ? 0.f   : hi[i][0];
            s[5] = kq ? 0.f   : hi[i][1];
            s[6] = kq ? 0.f   : hi[i][2];
            s[7] = kq ? 0.f   : hi[i][3];
            bfrag8 a;
            #pragma unroll
            for (int j = 0; j < 8; ++j) {
                __hip_bfloat16 h = __float2bfloat16(s[j]);
                a[j] = *(short*)&h;
            }
            accf16 acc0 = __builtin_amdgcn_mfma_f32_32x32x16_bf16(a, b0, z, 0, 0, 0);
            accf16 acc1 = __builtin_amdgcn_mfma_f32_32x32x16_bf16(a, b1, z, 0, 0, 0);

            float v0 = max16(acc0);
            float v1 = max16(acc1);
            v0 = fmaxf(v0, __shfl_xor(v0, 32));
            v1 = fmaxf(v1, __shfl_xor(v1, 32));
            float r = (lane < 32) ? v0 : v1;   // channel = lane
            r += sh;
            r = r > 0.f ? r : 0.f;

            feat_cell[(size_t)ent[pi].x * NC + lane] = r;   // unconditional
        }
    }
}

// Fallback (ws too small for compact path): dense streaming, direct scattered
// out write. Unchanged from prior session.
__global__ void __launch_bounds__(256) feat_dense_fallback(
    const float* __restrict__ pillars,
    const unsigned short* __restrict__ btab,
    const float* __restrict__ shift,
    const int*   __restrict__ idx,
    const int*   __restrict__ winner,
    float* __restrict__ out)
{
    int tid  = threadIdx.x;
    int lane = tid & 63;
    int wave = blockIdx.x * 4 + (tid >> 6);
    int row  = lane & 31;
    int kq   = lane >> 5;
    int b    = wave / (NP / PPW);

    bfrag8 b0 = *(const bfrag8*)(btab + lane * 8);
    bfrag8 b1 = *(const bfrag8*)(btab + (64 + lane) * 8);
    float  sh = shift[lane];
    accf16 z  = {};

    int cellv[PPW];
    bool winv[PPW];
    #pragma unroll
    for (int i = 0; i < PPW; ++i) {
        int pil = wave * PPW + i;
        int y = idx[pil * 3 + 1];
        int x = idx[pil * 3 + 2];
        x = x < 0 ? 0 : (x > 143 ? 143 : x);
        y = y < 0 ? 0 : (y > 143 ? 143 : y);
        int cell = y * NX + x;
        cellv[i] = cell;
        winv[i]  = (winner[b * NCELL + cell] == pil - b * NP);
    }

    const float* wbase = pillars + (size_t)wave * (PPW * NM * NF) + row * NF;

    #pragma unroll
    for (int g = 0; g < PPW / 4; ++g) {
        f32x4u lo[4], hi[4];
        float  e8[4];
        #pragma unroll
        for (int i = 0; i < 4; ++i) {
            const float* base = wbase + (size_t)(g * 4 + i) * (NM * NF);
            lo[i] = *(const f32x4u*)(base);
            hi[i] = *(const f32x4u*)(base + 4);
            e8[i] = base[8];
        }
        #pragma unroll
        for (int i = 0; i < 4; ++i) {
            int pi = g * 4 + i;
            float s[8];
            s[0] = kq ? e8[i] : lo[i][0];
            s[1] = kq ? 0.f   : lo[i][1];
            s[2] = kq ? 0.f   : lo[i][2];
            s[3] = kq ? 0.f   : lo[i][3];
            s[4] = kq ? 0.f   : hi[i][0];
            s[5] = kq ? 0.f   : hi[i][1];
            s[6] = kq ? 0.f   : hi[i][2];
            s[7] = kq ? 0.f   : hi[i][3];
            bfrag8 a;
            #pragma unroll
            for (int j = 0; j < 8; ++j) {
                __hip_bfloat16 h = __float2bfloat16(s[j]);
                a[j] = *(short*)&h;
            }
            accf16 acc0 = __builtin_amdgcn_mfma_f32_32x32x16_bf16(a, b0, z, 0, 0, 0);
            accf16 acc1 = __builtin_amdgcn_mfma_f32_32x32x16_bf16(a, b1, z, 0, 0, 0);

            float v0 = max16(acc0);
            float v1 = max16(acc1);
            v0 = fmaxf(v0, __shfl_xor(v0, 32));
            v1 = fmaxf(v1, __shfl_xor(v1, 32));
            float r = (lane < 32) ? v0 : v1;
            r += sh;
            r = r > 0.f ? r : 0.f;

            if (winv[pi]) {
                out[((size_t)(b * NC + lane)) * NCELL + cellv[pi]] = r;
            }
        }
    }
}

// Pass 3: dense LDS transpose. Load phase remapped to lane==cell:
//   - winner read is one coalesced 256B segment per wave (was 4 thr/cell)
//   - LDS write banks = cell%32 -> 2-way (free) instead of 4-way at stride 68
// Read phase unchanged: 16B-aligned ds_read_b128, 2-way (free).
__global__ void __launch_bounds__(256) scatter_t_kernel(
    const int* __restrict__ winner,
    const float* __restrict__ feat_cell,
    float* __restrict__ out)
{
    __shared__ float ld[NC * 68];            // stride 68 floats, 17.4 KB
    int tile = blockIdx.x;                   // [0, NB*324)
    int b    = tile / TILES_PER_B;
    int cb   = (tile - b * TILES_PER_B) * 64;
    int t    = threadIdx.x;

    // load phase: wave w owns channels [w*16, w*16+16), lane = cell
    {
        int cell = t & 63;
        int c0   = (t >> 6) * 16;            // channel base for this wave
        int win  = winner[b * NCELL + cb + cell];
        const f32x4u* src = (const f32x4u*)(feat_cell +
                             ((size_t)(b * NCELL + cb + cell)) * NC + c0);
        #pragma unroll
        for (int k = 0; k < 4; ++k) {
            f32x4u v = {0.f, 0.f, 0.f, 0.f};
            if (win >= 0) v = src[k];        // masked load: losers skip fetch
            int c = c0 + k * 4;
            ld[(c + 0) * 68 + cell] = v[0];  // banks = cell%32: conflict-free
            ld[(c + 1) * 68 + cell] = v[1];
            ld[(c + 2) * 68 + cell] = v[2];
            ld[(c + 3) * 68 + cell] = v[3];
        }
    }
    __syncthreads();
    // write phase: thread t -> c = t>>2, quarter qq = t&3 (16 cells as 4 float4)
    {
        int c = t >> 2, qq = t & 3;
        float* o = out + ((size_t)(b * NC + c)) * NCELL + cb + qq * 16;
        const float* lrow = ld + c * 68 + qq * 16;
        #pragma unroll
        for (int k = 0; k < 4; ++k) {
            *(f32x4u*)(o + k * 4) = *(const f32x4u*)(lrow + k * 4);
        }
    }
}

extern "C" void kernel_launch(void* const* d_in, const int* in_sizes, int n_in,
                              void* d_out, int out_size, void* d_ws, size_t ws_size,
                              hipStream_t stream) {
    const float* pillars = (const float*)d_in[0];
    const int*   idx     = (const int*)d_in[1];
    const float* conv_w  = (const float*)d_in[2];
    const float* gamma   = (const float*)d_in[3];
    const float* beta    = (const float*)d_in[4];
    const float* mean    = (const float*)d_in[5];
    const float* var     = (const float*)d_in[6];
    float* out = (float*)d_out;

    char* ws = (char*)d_ws;
    unsigned short* btab      = (unsigned short*)(ws + WS_BTAB);
    float*          shift     = (float*)(ws + WS_SHIFT);
    int*            cnt       = (int*)(ws + WS_CNT);
    int*            winner    = (int*)(ws + WS_WIN);
    int2*           list      = (int2*)(ws + WS_LIST);
    float*          feat_cell = (float*)(ws + WS_CELL);

    const bool compact = ws_size >= WS_NEED;   // constant per session

    hipMemsetAsync(winner, 0xFF, (size_t)NB * NCELL * sizeof(int), stream);
    winner_prep_kernel<<<(NB * NP + 255) / 256, 256, 0, stream>>>(
        idx, winner, conv_w, gamma, beta, mean, var, btab, shift, cnt);

    if (compact) {
        compact_kernel<<<(NB * NCELL + 255) / 256, 256, 0, stream>>>(
            winner, cnt, list);
        feat_list_kernel<<<FEAT_BLOCKS, 256, 0, stream>>>(
            pillars, btab, shift, cnt, list, feat_cell);
        scatter_t_kernel<<<NB * TILES_PER_B, 256, 0, stream>>>(
            winner, feat_cell, out);
    } else {
        hipMemsetAsync(out, 0, (size_t)out_size * sizeof(float), stream);
        feat_dense_fallback<<<FEAT_BLOCKS, 256, 0, stream>>>(
            pillars, btab, shift, idx, winner, out);
    }
}

// Round 3
// 211.384 us; speedup vs baseline: 1.1434x; 1.1434x over previous
//
#include <hip/hip_runtime.h>
#include <hip/hip_bf16.h>
#include <stdint.h>

#define NB 8
#define NP 12000
#define NM 32
#define NF 9
#define NC 64
#define NX 144
#define NCELL (144*144)          // 20736 = 64*324

#define PPW 8                    // pillars per wave
#define FEAT_WAVES ((NB*NP)/PPW) // 12000 (1500/batch -> no batch straddle)
#define FEAT_BLOCKS (FEAT_WAVES/4)
#define TILES_PER_B (NCELL/64)   // 324

typedef __attribute__((ext_vector_type(8)))  short bfrag8;
typedef __attribute__((ext_vector_type(16))) float accf16;
typedef float f32x4u __attribute__((ext_vector_type(4), aligned(4)));

// ws layout:
//   [0,2048)         btab: 2 c-tiles x 64 lanes x 8 bf16 (B-frag, BN-folded)
//   [2048,2304)      shift[c]
//   [4096,667648)    winner[b][cell] (8*20736 ints)
//   [667648,1051648) win_cell[pillar]: cell if this pillar is its cell's
//                    winner, else -1 (96000 ints)
//   [1051648,+42.47M) feat_cell[(b*NCELL+cell)*64 + c]  (winner cells only)
#define WS_BTAB  0
#define WS_SHIFT 2048
#define WS_WIN   4096
#define WS_FLAG  667648
#define WS_CELL  1051648
#define WS_NEED  (WS_CELL + (size_t)NB*NCELL*NC*4)

// Pass 1: last-write-wins winner (largest p wins) + BN-folded weight prep.
__global__ void winner_prep_kernel(const int* __restrict__ idx, int* __restrict__ winner,
                                   const float* __restrict__ conv_w,
                                   const float* __restrict__ gamma,
                                   const float* __restrict__ beta,
                                   const float* __restrict__ mean,
                                   const float* __restrict__ var,
                                   unsigned short* __restrict__ btab,
                                   float* __restrict__ shift)
{
    int t = blockIdx.x * blockDim.x + threadIdx.x;
    if (t < NB * NP) {
        int b = t / NP;
        int p = t - b * NP;
        int y = idx[t * 3 + 1];
        int x = idx[t * 3 + 2];
        x = x < 0 ? 0 : (x > 143 ? 143 : x);
        y = y < 0 ? 0 : (y > 143 ? 143 : y);
        atomicMax(&winner[b * NCELL + y * NX + x], p);   // init = -1
    }
    if (blockIdx.x == 0) {
        int tt = threadIdx.x;
        if (tt < 128) {
            int ct = tt >> 6, L = tt & 63;
            int c  = ct * 32 + (L & 31);
            int kq = L >> 5;
            float sc = gamma[c] * rsqrtf(var[c] + 1e-5f);
            unsigned short* dst = btab + (ct * 64 + L) * 8;
            #pragma unroll
            for (int j = 0; j < 8; ++j) {
                int k = kq * 8 + j;
                float w = (k < NF) ? conv_w[c * NF + k] * sc : 0.f;
                __hip_bfloat16 h = __float2bfloat16(w);
                dst[j] = *(unsigned short*)&h;
            }
        }
        if (tt < NC) {
            float sc = gamma[tt] * rsqrtf(var[tt] + 1e-5f);
            shift[tt] = beta[tt] - mean[tt] * sc;
        }
    }
}

// Pass 1b: per-pillar winner flag. One fully-parallel gather per pillar
// (no serial chain: idx read is coalesced, winner gather is L2-resident).
// Moves the feat kernel's 24 serialized gathers/wave into ~3 us of slack.
__global__ void flag_kernel(const int* __restrict__ idx,
                            const int* __restrict__ winner,
                            int* __restrict__ win_cell)
{
    int t = blockIdx.x * blockDim.x + threadIdx.x;
    if (t >= NB * NP) return;
    int b = t / NP;
    int p = t - b * NP;
    int y = idx[t * 3 + 1];
    int x = idx[t * 3 + 2];
    x = x < 0 ? 0 : (x > 143 ? 143 : x);
    y = y < 0 ? 0 : (y > 143 ? 143 : y);
    int cell = y * NX + x;
    win_cell[t] = (winner[b * NCELL + cell] == p) ? cell : -1;
}

__device__ __forceinline__ float max16(const accf16& a) {
    float t0 = fmaxf(fmaxf(a[0], a[1]),  fmaxf(a[2], a[3]));
    float t1 = fmaxf(fmaxf(a[4], a[5]),  fmaxf(a[6], a[7]));
    float t2 = fmaxf(fmaxf(a[8], a[9]),  fmaxf(a[10], a[11]));
    float t3 = fmaxf(fmaxf(a[12], a[13]), fmaxf(a[14], a[15]));
    return fmaxf(fmaxf(t0, t1), fmaxf(t2, t3));
}

// Pass 2: dense streaming conv+max (pillars read fully coalesced, in order).
// Per-pillar metadata now comes from ONE coalesced win_cell load + 8 shfl
// broadcasts instead of 16 idx loads + 8 dependent winner gathers.
template <bool COMPACT>
__global__ void __launch_bounds__(256) feat_dense_kernel(
    const float* __restrict__ pillars,
    const unsigned short* __restrict__ btab,
    const float* __restrict__ shift,
    const int*   __restrict__ win_cell,
    float* __restrict__ feat_cell,
    float* __restrict__ out)
{
    int tid  = threadIdx.x;
    int lane = tid & 63;
    int wave = blockIdx.x * 4 + (tid >> 6);
    int row  = lane & 31;
    int kq   = lane >> 5;
    int b    = wave / (NP / PPW);            // 1500 waves per batch, no straddle

    bfrag8 b0 = *(const bfrag8*)(btab + lane * 8);
    bfrag8 b1 = *(const bfrag8*)(btab + (64 + lane) * 8);
    float  sh = shift[lane];
    accf16 z  = {};

    // wave-uniform per-pillar metadata: 1 coalesced load + 8 broadcasts
    int wc_mine = win_cell[wave * PPW + (lane & 7)];
    int cellv[PPW];
    bool winv[PPW];
    #pragma unroll
    for (int i = 0; i < PPW; ++i) {
        int wc = __shfl(wc_mine, i);
        cellv[i] = wc;
        winv[i]  = wc >= 0;
    }

    const float* wbase = pillars + (size_t)wave * (PPW * NM * NF) + row * NF;

    #pragma unroll
    for (int g = 0; g < PPW / 4; ++g) {
        f32x4u lo[4], hi[4];
        float  e8[4];
        #pragma unroll
        for (int i = 0; i < 4; ++i) {
            const float* base = wbase + (size_t)(g * 4 + i) * (NM * NF);
            lo[i] = *(const f32x4u*)(base);
            hi[i] = *(const f32x4u*)(base + 4);
            e8[i] = base[8];
        }
        #pragma unroll
        for (int i = 0; i < 4; ++i) {
            int pi = g * 4 + i;
            float s[8];
            s[0] = kq ? e8[i] : lo[i][0];
            s[1] = kq ? 0.f   : lo[i][1];
            s[2] = kq ? 0.f   : lo[i][2];
            s[3] = kq ? 0.f   : lo[i][3];
            s[4] = kq ? 0.f   : hi[i][0];
            s[5] = kq ? 0.f   : hi[i][1];
            s[6] = kq ? 0.f   : hi[i][2];
            s[7] = kq ? 0.f   : hi[i][3];
            bfrag8 a;
            #pragma unroll
            for (int j = 0; j < 8; ++j) {
                __hip_bfloat16 h = __float2bfloat16(s[j]);
                a[j] = *(short*)&h;
            }
            accf16 acc0 = __builtin_amdgcn_mfma_f32_32x32x16_bf16(a, b0, z, 0, 0, 0);
            accf16 acc1 = __builtin_amdgcn_mfma_f32_32x32x16_bf16(a, b1, z, 0, 0, 0);

            float v0 = max16(acc0);
            float v1 = max16(acc1);
            v0 = fmaxf(v0, __shfl_xor(v0, 32));
            v1 = fmaxf(v1, __shfl_xor(v1, 32));
            float r = (lane < 32) ? v0 : v1;   // channel = lane
            r += sh;
            r = r > 0.f ? r : 0.f;

            if (winv[pi]) {                    // wave-uniform branch
                if (COMPACT) {
                    feat_cell[((size_t)b * NCELL + cellv[pi]) * NC + lane] = r;
                } else {
                    out[((size_t)(b * NC + lane)) * NCELL + cellv[pi]] = r;
                }
            }
        }
    }
}

// Pass 3: dense LDS transpose (proven round-0 mapping). Block = (b, 64-cell
// tile). Read feat_cell coalesced (loser lanes exec-masked -> load skipped),
// zero-fill losers, transpose via LDS, write out coalesced float4.
__global__ void __launch_bounds__(256) scatter_t_kernel(
    const int* __restrict__ winner,
    const float* __restrict__ feat_cell,
    float* __restrict__ out)
{
    __shared__ float ld[NC * 68];            // stride 68 floats, 17.4 KB
    int tile = blockIdx.x;                   // [0, NB*324)
    int b    = tile / TILES_PER_B;
    int cb   = (tile - b * TILES_PER_B) * 64;
    int t    = threadIdx.x;

    // load phase: thread t -> cell = t>>2, quarter q = t&3 (16 ch as 4 float4)
    {
        int cell = t >> 2, q = t & 3;
        int w = winner[b * NCELL + cb + cell];
        const f32x4u* src = (const f32x4u*)(feat_cell +
                             ((size_t)(b * NCELL + cb + cell)) * NC);
        #pragma unroll
        for (int k = 0; k < 4; ++k) {
            f32x4u v = {0.f, 0.f, 0.f, 0.f};
            if (w >= 0) v = src[q * 4 + k];  // masked load: losers skip fetch
            int c = q * 16 + k * 4;
            ld[(c + 0) * 68 + cell] = v[0];  // transpose on LDS write
            ld[(c + 1) * 68 + cell] = v[1];
            ld[(c + 2) * 68 + cell] = v[2];
            ld[(c + 3) * 68 + cell] = v[3];
        }
    }
    __syncthreads();
    // write phase: thread t -> c = t>>2, quarter qq = t&3 (16 cells as 4 float4)
    {
        int c = t >> 2, qq = t & 3;
        float* o = out + ((size_t)(b * NC + c)) * NCELL + cb + qq * 16;
        const float* lrow = ld + c * 68 + qq * 16;
        #pragma unroll
        for (int k = 0; k < 4; ++k) {
            *(f32x4u*)(o + k * 4) = *(const f32x4u*)(lrow + k * 4);
        }
    }
}

extern "C" void kernel_launch(void* const* d_in, const int* in_sizes, int n_in,
                              void* d_out, int out_size, void* d_ws, size_t ws_size,
                              hipStream_t stream) {
    const float* pillars = (const float*)d_in[0];
    const int*   idx     = (const int*)d_in[1];
    const float* conv_w  = (const float*)d_in[2];
    const float* gamma   = (const float*)d_in[3];
    const float* beta    = (const float*)d_in[4];
    const float* mean    = (const float*)d_in[5];
    const float* var     = (const float*)d_in[6];
    float* out = (float*)d_out;

    char* ws = (char*)d_ws;
    unsigned short* btab      = (unsigned short*)(ws + WS_BTAB);
    float*          shift     = (float*)(ws + WS_SHIFT);
    int*            winner    = (int*)(ws + WS_WIN);
    int*            win_cell  = (int*)(ws + WS_FLAG);
    float*          feat_cell = (float*)(ws + WS_CELL);

    const bool compact = ws_size >= WS_NEED;   // constant per session

    hipMemsetAsync(winner, 0xFF, (size_t)NB * NCELL * sizeof(int), stream);
    winner_prep_kernel<<<(NB * NP + 255) / 256, 256, 0, stream>>>(
        idx, winner, conv_w, gamma, beta, mean, var, btab, shift);
    flag_kernel<<<(NB * NP + 255) / 256, 256, 0, stream>>>(
        idx, winner, win_cell);

    if (compact) {
        feat_dense_kernel<true><<<FEAT_BLOCKS, 256, 0, stream>>>(
            pillars, btab, shift, win_cell, feat_cell, out);
        scatter_t_kernel<<<NB * TILES_PER_B, 256, 0, stream>>>(
            winner, feat_cell, out);
    } else {
        hipMemsetAsync(out, 0, (size_t)out_size * sizeof(float), stream);
        feat_dense_kernel<false><<<FEAT_BLOCKS, 256, 0, stream>>>(
            pillars, btab, shift, win_cell, feat_cell, out);
    }
}